// Round 1
// baseline (1528.534 us; speedup 1.0000x reference)
//
#include <hip/hip_runtime.h>

#define NAT 20000
#define NE  640000
#define NT  2000000
#define CH  128
#define EF  64
#define NB  4096
#define PI_F 3.14159265358979f

typedef __attribute__((ext_vector_type(8))) __bf16 bf16x8;
typedef __attribute__((ext_vector_type(4))) float floatx4;

__device__ __forceinline__ float fsigmoid(float x) {
    return __builtin_amdgcn_rcpf(1.0f + __expf(-x));
}
__device__ __forceinline__ float fsilu(float x) { return x * fsigmoid(x); }

// ---------------- K1/K6: Y[M x 128] = X[M x 128] @ W[128 x 128] ----------------
__global__ __launch_bounds__(256) void gemm128(const float* __restrict__ X,
                                               const float* __restrict__ W,
                                               float* __restrict__ Y) {
    __shared__ float Xs[32 * 128];
    __shared__ float Ws[32 * 128];
    int tid = threadIdx.x;
    int row0 = blockIdx.x * 32;

    const float4* Xg = (const float4*)(X + (size_t)row0 * 128);
    float4* Xs4 = (float4*)Xs;
#pragma unroll
    for (int i = 0; i < 4; ++i) Xs4[tid + 256 * i] = Xg[tid + 256 * i];

    int c = tid & 127, half = tid >> 7;
    float acc[16];
#pragma unroll
    for (int r = 0; r < 16; ++r) acc[r] = 0.0f;

    for (int kb = 0; kb < 4; ++kb) {
        __syncthreads();  // protect Ws overwrite (and Xs stores on first iter)
        const float4* Wg = (const float4*)(W + kb * 32 * 128);
        float4* Ws4 = (float4*)Ws;
#pragma unroll
        for (int i = 0; i < 4; ++i) Ws4[tid + 256 * i] = Wg[tid + 256 * i];
        __syncthreads();
#pragma unroll
        for (int kk = 0; kk < 32; ++kk) {
            float wv = Ws[kk * 128 + c];
            int k = kb * 32 + kk;
#pragma unroll
            for (int r = 0; r < 16; ++r)
                acc[r] += Xs[(half * 16 + r) * 128 + k] * wv;
        }
    }
#pragma unroll
    for (int r = 0; r < 16; ++r)
        Y[(size_t)(row0 + half * 16 + r) * 128 + c] = acc[r];
}

// ---------------- K2: build two-body LUT: lut[p][c] = gated_mlp(rb(d_p))[c] ----------------
__global__ __launch_bounds__(128) void build_lut(const float* __restrict__ W1,
                                                 const float* __restrict__ W2,
                                                 const float* __restrict__ G1,
                                                 const float* __restrict__ G2,
                                                 float* __restrict__ lut) {
    __shared__ float rb[64], hm[64], hg[64];
    int p = blockIdx.x, t = threadIdx.x;
    float d = p * (5.0f / NB);
    if (t < 64) {
        float ctr = t * (5.0f / 63.0f);
        float sig = 5.0f / 64.0f;
        float z = (d - ctr);
        float g = __expf(-z * z / (2.0f * sig * sig));
        float env = (d < 5.0f) ? 0.5f * (1.0f + __cosf(PI_F * d / 5.0f)) : 0.0f;
        rb[t] = g * env;
    }
    __syncthreads();
    {
        int j = t & 63;
        const float* Wm = (t < 64) ? W1 : G1;
        float s = 0.0f;
        for (int k = 0; k < 64; ++k) s += rb[k] * Wm[k * 64 + j];
        float hv = fsilu(s);
        if (t < 64) hm[j] = hv; else hg[j] = hv;
    }
    __syncthreads();
    {
        float m = 0.0f, g = 0.0f;
        for (int j = 0; j < 64; ++j) {
            m += hm[j] * W2[j * 128 + t];
            g += hg[j] * G2[j * 128 + t];
        }
        lut[(size_t)p * 128 + t] = m * fsigmoid(g);
    }
}

// ---------------- K3: two-body edges: acc[nl0[e]] += h[nl1[e]] * lut(d_e) ----------------
__global__ __launch_bounds__(256) void twobody(const float* __restrict__ dist,
                                               const int* __restrict__ nl,
                                               const float* __restrict__ h,
                                               const float* __restrict__ lut,
                                               float* __restrict__ acc) {
    int lane = threadIdx.x & 63;
    int wid = blockIdx.x * 4 + (threadIdx.x >> 6);
    int nw = gridDim.x * 4;
    int c = lane << 1;
    for (int e = wid; e < NE; e += nw) {
        float d = dist[e];
        int a0 = nl[e], a1 = nl[NE + e];
        float x = d * ((float)NB / 5.0f);
        int i0 = (int)x;
        if (i0 > NB - 1) i0 = NB - 1;
        float f = x - (float)i0;
        float2 l0 = *(const float2*)&lut[(size_t)i0 * 128 + c];
        float2 l1 = *(const float2*)&lut[(size_t)(i0 + 1) * 128 + c];
        float2 hv = *(const float2*)&h[(size_t)a1 * 128 + c];
        float t0 = l0.x + (l1.x - l0.x) * f;
        float t1 = l0.y + (l1.y - l0.y) * f;
        unsafeAtomicAdd(&acc[(size_t)a0 * 128 + c], hv.x * t0);
        unsafeAtomicAdd(&acc[(size_t)a0 * 128 + c + 1], hv.y * t1);
    }
}

// ---------------- K4: three-body: W3[idx1[t]] += gated_mlp(f3_t) ----------------
__global__ __launch_bounds__(256) void threebody(const float* __restrict__ rij,
                                                 const float* __restrict__ rik,
                                                 const float* __restrict__ ang,
                                                 const int* __restrict__ tri,
                                                 const float* __restrict__ thW1,
                                                 const float* __restrict__ thW2,
                                                 const float* __restrict__ thG1,
                                                 const float* __restrict__ thG2,
                                                 float* __restrict__ W3) {
    __shared__ __bf16 lw2[64 * 128];
    __shared__ __bf16 lg2[64 * 128];
    __shared__ float lw1[192];
    __shared__ float lg1[192];
    int tid = threadIdx.x;
    for (int i = tid; i < 192; i += 256) { lw1[i] = thW1[i]; lg1[i] = thG1[i]; }
    // Stage W2/G2 as bf16, pre-swizzled into B-fragment order:
    // element (k,c): tile=c>>4, n=c&15, s=k>>5, q=(k>>3)&3, j=k&7
    // lds index = (((tile*2+s)*64) + q*16 + n)*8 + j  -> frag is 8 contiguous bf16 (16B)
    for (int e = tid; e < 64 * 128; e += 256) {
        int k = e >> 7, c = e & 127;
        int tile = c >> 4, n = c & 15, s = k >> 5, q = (k >> 3) & 3, j = k & 7;
        int li = ((((tile << 1) + s) * 64) + (q << 4) + n) * 8 + j;
        lw2[li] = (__bf16)thW2[e];
        lg2[li] = (__bf16)thG2[e];
    }
    __syncthreads();

    int lane = tid & 63;
    int q = lane >> 4, n = lane & 15;
    int wid = (blockIdx.x << 2) + (tid >> 6);
    int nw = gridDim.x << 2;

    for (int chunk = wid; chunk < NT / 64; chunk += nw) {
        int t0 = chunk << 6;
        // Each lane loads one triplet's raw data; redistribute by shuffle.
        float rl = rij[t0 + lane];
        float kl = rik[t0 + lane];
        float cl = __cosf(ang[t0 + lane]);
        int il = tri[(size_t)(t0 + lane) * 3 + 1];

        float rm[4], km[4], cm[4];
#pragma unroll
        for (int ms = 0; ms < 4; ++ms) {
            int src = (ms << 4) + n;   // A-operand: m = lane&15
            rm[ms] = __shfl(rl, src);
            km[ms] = __shfl(kl, src);
            cm[ms] = __shfl(cl, src);
        }

        // hidden activations -> bf16 A-fragments (A[m=lane&15][k=q*8+j], k-step s)
        bf16x8 fam[4][2], fag[4][2];
#pragma unroll
        for (int s = 0; s < 2; ++s)
#pragma unroll
            for (int j = 0; j < 8; ++j) {
                int k = s * 32 + (q << 3) + j;
                float a0 = lw1[k], a1 = lw1[64 + k], a2 = lw1[128 + k];
                float b0 = lg1[k], b1 = lg1[64 + k], b2 = lg1[128 + k];
#pragma unroll
                for (int ms = 0; ms < 4; ++ms) {
                    float um = rm[ms] * a0 + km[ms] * a1 + cm[ms] * a2;
                    float ug = rm[ms] * b0 + km[ms] * b1 + cm[ms] * b2;
                    fam[ms][s][j] = (__bf16)fsilu(um);
                    fag[ms][s][j] = (__bf16)fsilu(ug);
                }
            }

        // atom index for each output row (C/D: row = q*4+reg)
        int irow[16];
#pragma unroll
        for (int rr = 0; rr < 16; ++rr)
            irow[rr] = __shfl(il, ((rr >> 2) << 4) + (q << 2) + (rr & 3));

#pragma unroll
        for (int tile = 0; tile < 8; ++tile) {
            int base0 = ((((tile << 1) + 0) * 64) + (q << 4) + n) << 3;
            int base1 = ((((tile << 1) + 1) * 64) + (q << 4) + n) << 3;
            bf16x8 bw0 = *(const bf16x8*)&lw2[base0];
            bf16x8 bw1 = *(const bf16x8*)&lw2[base1];
            bf16x8 bg0 = *(const bf16x8*)&lg2[base0];
            bf16x8 bg1 = *(const bf16x8*)&lg2[base1];
#pragma unroll
            for (int ms = 0; ms < 4; ++ms) {
                floatx4 am = {0.f, 0.f, 0.f, 0.f};
                floatx4 ag = {0.f, 0.f, 0.f, 0.f};
                am = __builtin_amdgcn_mfma_f32_16x16x32_bf16(fam[ms][0], bw0, am, 0, 0, 0);
                am = __builtin_amdgcn_mfma_f32_16x16x32_bf16(fam[ms][1], bw1, am, 0, 0, 0);
                ag = __builtin_amdgcn_mfma_f32_16x16x32_bf16(fag[ms][0], bg0, ag, 0, 0, 0);
                ag = __builtin_amdgcn_mfma_f32_16x16x32_bf16(fag[ms][1], bg1, ag, 0, 0, 0);
#pragma unroll
                for (int reg = 0; reg < 4; ++reg) {
                    float w3 = am[reg] * fsigmoid(ag[reg]);
                    int atom = irow[(ms << 2) + reg];
                    unsafeAtomicAdd(&W3[(size_t)atom * 128 + (tile << 4) + n], w3);
                }
            }
        }
    }
}

// ---------------- K5: inject three-body rows: acc[nl0[e]] += h[e]*W3[e], e<20000 ----------------
__global__ __launch_bounds__(256) void inject(const float* __restrict__ h,
                                              const float* __restrict__ W3,
                                              const int* __restrict__ nl,
                                              float* __restrict__ acc) {
    int g = blockIdx.x * 256 + threadIdx.x;  // covers 20000*128
    int row = g >> 7, c = g & 127;
    float v = h[g] * W3[g];
    unsafeAtomicAdd(&acc[(size_t)nl[row] * 128 + c], v);
}

extern "C" void kernel_launch(void* const* d_in, const int* in_sizes, int n_in,
                              void* d_out, int out_size, void* d_ws, size_t ws_size,
                              hipStream_t stream) {
    const float* features = (const float*)d_in[0];
    const float* dist = (const float*)d_in[1];
    const float* ang = (const float*)d_in[2];
    const float* rij = (const float*)d_in[3];
    const float* rik = (const float*)d_in[4];
    const int* nl = (const int*)d_in[5];
    const int* tri = (const int*)d_in[6];
    const float* W_pre = (const float*)d_in[7];
    const float* tbW1 = (const float*)d_in[8];
    const float* tbW2 = (const float*)d_in[9];
    const float* tbG1 = (const float*)d_in[10];
    const float* tbG2 = (const float*)d_in[11];
    const float* thW1 = (const float*)d_in[12];
    const float* thW2 = (const float*)d_in[13];
    const float* thG1 = (const float*)d_in[14];
    const float* thG2 = (const float*)d_in[15];
    const float* W_post = (const float*)d_in[16];
    float* out = (float*)d_out;

    float* h = (float*)d_ws;                 // 20000*128
    float* W3 = h + (size_t)NAT * CH;        // 20000*128
    float* acc = W3 + (size_t)NAT * CH;      // 20000*128
    float* lut = acc + (size_t)NAT * CH;     // (NB+1)*128

    // zero W3sum + acc (contiguous)
    hipMemsetAsync(W3, 0, (size_t)2 * NAT * CH * sizeof(float), stream);

    gemm128<<<NAT / 32, 256, 0, stream>>>(features, W_pre, h);
    build_lut<<<NB + 1, 128, 0, stream>>>(tbW1, tbW2, tbG1, tbG2, lut);
    twobody<<<2048, 256, 0, stream>>>(dist, nl, h, lut, acc);
    threebody<<<2048, 256, 0, stream>>>(rij, rik, ang, tri, thW1, thW2, thG1, thG2, W3);
    inject<<<NAT * CH / 256, 256, 0, stream>>>(h, W3, nl, acc);
    gemm128<<<NAT / 32, 256, 0, stream>>>(acc, W_post, out);
}

// Round 2
// 921.680 us; speedup vs baseline: 1.6584x; 1.6584x over previous
//
#include <hip/hip_runtime.h>

#define NAT 20000
#define NE  640000
#define NT  2000000
#define CH  128
#define EF  64
#define NB  4096
#define PI_F 3.14159265358979f

typedef __attribute__((ext_vector_type(8))) __bf16 bf16x8;
typedef __attribute__((ext_vector_type(4))) float floatx4;

__device__ __forceinline__ float fsigmoid(float x) {
    return __builtin_amdgcn_rcpf(1.0f + __expf(-x));
}
__device__ __forceinline__ float fsilu(float x) { return x * fsigmoid(x); }

// ---------------- K1/K6: Y[M x 128] = X[M x 128] @ W[128 x 128] ----------------
__global__ __launch_bounds__(256) void gemm128(const float* __restrict__ X,
                                               const float* __restrict__ W,
                                               float* __restrict__ Y) {
    __shared__ float Xs[32 * 128];
    __shared__ float Ws[32 * 128];
    int tid = threadIdx.x;
    int row0 = blockIdx.x * 32;

    const float4* Xg = (const float4*)(X + (size_t)row0 * 128);
    float4* Xs4 = (float4*)Xs;
#pragma unroll
    for (int i = 0; i < 4; ++i) Xs4[tid + 256 * i] = Xg[tid + 256 * i];

    int c = tid & 127, half = tid >> 7;
    float acc[16];
#pragma unroll
    for (int r = 0; r < 16; ++r) acc[r] = 0.0f;

    for (int kb = 0; kb < 4; ++kb) {
        __syncthreads();
        const float4* Wg = (const float4*)(W + kb * 32 * 128);
        float4* Ws4 = (float4*)Ws;
#pragma unroll
        for (int i = 0; i < 4; ++i) Ws4[tid + 256 * i] = Wg[tid + 256 * i];
        __syncthreads();
#pragma unroll
        for (int kk = 0; kk < 32; ++kk) {
            float wv = Ws[kk * 128 + c];
            int k = kb * 32 + kk;
#pragma unroll
            for (int r = 0; r < 16; ++r)
                acc[r] += Xs[(half * 16 + r) * 128 + k] * wv;
        }
    }
#pragma unroll
    for (int r = 0; r < 16; ++r)
        Y[(size_t)(row0 + half * 16 + r) * 128 + c] = acc[r];
}

// ---------------- K2: build two-body LUT ----------------
__global__ __launch_bounds__(128) void build_lut(const float* __restrict__ W1,
                                                 const float* __restrict__ W2,
                                                 const float* __restrict__ G1,
                                                 const float* __restrict__ G2,
                                                 float* __restrict__ lut) {
    __shared__ float rb[64], hm[64], hg[64];
    int p = blockIdx.x, t = threadIdx.x;
    float d = p * (5.0f / NB);
    if (t < 64) {
        float ctr = t * (5.0f / 63.0f);
        float sig = 5.0f / 64.0f;
        float z = (d - ctr);
        float g = __expf(-z * z / (2.0f * sig * sig));
        float env = (d < 5.0f) ? 0.5f * (1.0f + __cosf(PI_F * d / 5.0f)) : 0.0f;
        rb[t] = g * env;
    }
    __syncthreads();
    {
        int j = t & 63;
        const float* Wm = (t < 64) ? W1 : G1;
        float s = 0.0f;
        for (int k = 0; k < 64; ++k) s += rb[k] * Wm[k * 64 + j];
        float hv = fsilu(s);
        if (t < 64) hm[j] = hv; else hg[j] = hv;
    }
    __syncthreads();
    {
        float m = 0.0f, g = 0.0f;
        for (int j = 0; j < 64; ++j) {
            m += hm[j] * W2[j * 128 + t];
            g += hg[j] * G2[j * 128 + t];
        }
        lut[(size_t)p * 128 + t] = m * fsigmoid(g);
    }
}

// ---------------- sort passes: histogram, scan, scatter ----------------
__global__ __launch_bounds__(256) void hist_k(const int* __restrict__ tri,
                                              const int* __restrict__ nl,
                                              int* __restrict__ tcnt,
                                              int* __restrict__ ecnt) {
    int stride = gridDim.x * 256;
    for (int g = blockIdx.x * 256 + threadIdx.x; g < NT + NE; g += stride) {
        if (g < NT) atomicAdd(&tcnt[tri[(size_t)g * 3 + 1]], 1);
        else        atomicAdd(&ecnt[nl[g - NT]], 1);
    }
}

__global__ __launch_bounds__(1024) void scan20k(int* __restrict__ tcnt, int* __restrict__ toff, int* __restrict__ tcur,
                                                int* __restrict__ ecnt, int* __restrict__ eoff, int* __restrict__ ecur) {
    int* cnt; int* off; int* cur;
    if (blockIdx.x == 0) { cnt = tcnt; off = toff; cur = tcur; }
    else                 { cnt = ecnt; off = eoff; cur = ecur; }
    __shared__ int part[1024];
    int t = threadIdx.x;
    const int PER = 20;
    int vals[PER]; int lsum = 0;
#pragma unroll
    for (int i = 0; i < PER; ++i) {
        int idx = t * PER + i;
        int v = (idx < NAT) ? cnt[idx] : 0;
        vals[i] = v; lsum += v;
    }
    part[t] = lsum;
    __syncthreads();
    for (int d = 1; d < 1024; d <<= 1) {
        int add = (t >= d) ? part[t - d] : 0;
        __syncthreads();
        part[t] += add;
        __syncthreads();
    }
    int run = part[t] - lsum;
#pragma unroll
    for (int i = 0; i < PER; ++i) {
        int idx = t * PER + i;
        if (idx < NAT) { off[idx] = run; cur[idx] = run; run += vals[i]; }
    }
    if (t == 1023) off[NAT] = part[1023];
}

__global__ __launch_bounds__(256) void scatter_k(const int* __restrict__ tri,
                                                 const int* __restrict__ nl,
                                                 int* __restrict__ tcur, int* __restrict__ ecur,
                                                 int* __restrict__ tsorted, int* __restrict__ esorted) {
    int stride = gridDim.x * 256;
    for (int g = blockIdx.x * 256 + threadIdx.x; g < NT + NE; g += stride) {
        if (g < NT) {
            int p = atomicAdd(&tcur[tri[(size_t)g * 3 + 1]], 1);
            tsorted[p] = g;
        } else {
            int e = g - NT;
            int p = atomicAdd(&ecur[nl[e]], 1);
            esorted[p] = e;
        }
    }
}

// ---------------- K3: two-body, sorted by destination atom — no atomics ----------------
__global__ __launch_bounds__(256) void twobody_sorted(const float* __restrict__ dist,
                                                      const int* __restrict__ nl,
                                                      const float* __restrict__ h,
                                                      const float* __restrict__ lut,
                                                      const int* __restrict__ eoff,
                                                      const int* __restrict__ esorted,
                                                      float* __restrict__ acc) {
    int tid = threadIdx.x, lane = tid & 63;
    int wid = blockIdx.x * 4 + (tid >> 6);
    int nw = gridDim.x * 4;
    int c = lane << 1;
    for (int a = wid; a < NAT; a += nw) {
        int base = eoff[a];
        int cnt = eoff[a + 1] - base;
        float s0 = 0.f, s1 = 0.f;
        for (int i0 = 0; i0 < cnt; i0 += 64) {
            int rem = cnt - i0; if (rem > 64) rem = 64;
            float dl = 0.f; int a1l = 0;
            if (lane < rem) {
                int e = esorted[base + i0 + lane];
                dl = dist[e];
                a1l = nl[NE + e];
            }
            for (int j = 0; j < rem; ++j) {
                float d = __shfl(dl, j);
                int a1 = __shfl(a1l, j);
                float x = d * ((float)NB / 5.0f);
                int i = (int)x; if (i > NB - 1) i = NB - 1;
                float f = x - (float)i;
                float2 l0 = *(const float2*)&lut[(size_t)i * 128 + c];
                float2 l1 = *(const float2*)&lut[(size_t)(i + 1) * 128 + c];
                float2 hv = *(const float2*)&h[(size_t)a1 * 128 + c];
                s0 += hv.x * (l0.x + (l1.x - l0.x) * f);
                s1 += hv.y * (l0.y + (l1.y - l0.y) * f);
            }
        }
        acc[(size_t)a * 128 + c] = s0;
        acc[(size_t)a * 128 + c + 1] = s1;
    }
}

// ---------------- K4: three-body, sorted by center atom — register accumulation ----------------
__global__ __launch_bounds__(256) void threebody_sorted(const float* __restrict__ rij,
                                                        const float* __restrict__ rik,
                                                        const float* __restrict__ ang,
                                                        const int* __restrict__ tsorted,
                                                        const int* __restrict__ toff,
                                                        const float* __restrict__ thW1,
                                                        const float* __restrict__ thW2,
                                                        const float* __restrict__ thG1,
                                                        const float* __restrict__ thG2,
                                                        float* __restrict__ W3) {
    __shared__ __bf16 lw2[64 * 128];
    __shared__ __bf16 lg2[64 * 128];
    __shared__ float lw1[192];
    __shared__ float lg1[192];
    int tid = threadIdx.x;
    for (int i = tid; i < 192; i += 256) { lw1[i] = thW1[i]; lg1[i] = thG1[i]; }
    // B-fragment swizzle (validated in round 0): element (k,c) ->
    // lds index (((tile*2+s)*64) + q*16 + n)*8 + j; frag = 8 contiguous bf16
    for (int e = tid; e < 64 * 128; e += 256) {
        int k = e >> 7, c = e & 127;
        int tile = c >> 4, n = c & 15, s = k >> 5, q = (k >> 3) & 3, j = k & 7;
        int li = ((((tile << 1) + s) * 64) + (q << 4) + n) * 8 + j;
        lw2[li] = (__bf16)thW2[e];
        lg2[li] = (__bf16)thG2[e];
    }
    __syncthreads();

    int lane = tid & 63;
    int q = lane >> 4, n = lane & 15;
    int wid = (blockIdx.x << 2) + (tid >> 6);
    int nw = gridDim.x << 2;

    for (int a = wid; a < NAT; a += nw) {
        int base = toff[a];
        int cnt = toff[a + 1] - base;
        float accT[8][4];
#pragma unroll
        for (int tt = 0; tt < 8; ++tt)
#pragma unroll
            for (int r = 0; r < 4; ++r) accT[tt][r] = 0.f;

        for (int b0 = 0; b0 < cnt; b0 += 16) {
            // lane's A-row m = n = lane&15; 4 q-groups redundantly load (cache-merged)
            float rr = 0.f, kk = 0.f, cc = 0.f;
            if (n < cnt - b0) {
                int trip = tsorted[base + b0 + n];
                rr = rij[trip];
                kk = rik[trip];
                cc = __cosf(ang[trip]);
            }
            // hidden activations -> bf16 A-fragments: A[m=lane&15][k=q*8+j], k-step s
            bf16x8 fam[2], fag[2];
#pragma unroll
            for (int s = 0; s < 2; ++s)
#pragma unroll
                for (int j = 0; j < 8; ++j) {
                    int k = s * 32 + (q << 3) + j;
                    float um = rr * lw1[k] + kk * lw1[64 + k] + cc * lw1[128 + k];
                    float ug = rr * lg1[k] + kk * lg1[64 + k] + cc * lg1[128 + k];
                    fam[s][j] = (__bf16)fsilu(um);
                    fag[s][j] = (__bf16)fsilu(ug);
                }
#pragma unroll
            for (int tile = 0; tile < 8; ++tile) {
                int b0i = ((((tile << 1) + 0) * 64) + (q << 4) + n) << 3;
                int b1i = ((((tile << 1) + 1) * 64) + (q << 4) + n) << 3;
                bf16x8 bw0 = *(const bf16x8*)&lw2[b0i];
                bf16x8 bw1 = *(const bf16x8*)&lw2[b1i];
                bf16x8 bg0 = *(const bf16x8*)&lg2[b0i];
                bf16x8 bg1 = *(const bf16x8*)&lg2[b1i];
                floatx4 am = {0.f, 0.f, 0.f, 0.f};
                floatx4 ag = {0.f, 0.f, 0.f, 0.f};
                am = __builtin_amdgcn_mfma_f32_16x16x32_bf16(fam[0], bw0, am, 0, 0, 0);
                am = __builtin_amdgcn_mfma_f32_16x16x32_bf16(fam[1], bw1, am, 0, 0, 0);
                ag = __builtin_amdgcn_mfma_f32_16x16x32_bf16(fag[0], bg0, ag, 0, 0, 0);
                ag = __builtin_amdgcn_mfma_f32_16x16x32_bf16(fag[1], bg1, ag, 0, 0, 0);
#pragma unroll
                for (int r = 0; r < 4; ++r)
                    accT[tile][r] += am[r] * fsigmoid(ag[r]);
            }
        }
        // reduce over the 16 C-rows: 4 regs in-lane + q-groups via xor-shuffle
#pragma unroll
        for (int tile = 0; tile < 8; ++tile) {
            float v = accT[tile][0] + accT[tile][1] + accT[tile][2] + accT[tile][3];
            v += __shfl_xor(v, 16);
            v += __shfl_xor(v, 32);
            if (q == 0) W3[(size_t)a * 128 + (tile << 4) + n] = v;
        }
    }
}

// ---------------- K5: inject three-body rows: acc[nl0[e]] += h[e]*W3[e], e<20000 ----------------
__global__ __launch_bounds__(256) void inject(const float* __restrict__ h,
                                              const float* __restrict__ W3,
                                              const int* __restrict__ nl,
                                              float* __restrict__ acc) {
    int g = blockIdx.x * 256 + threadIdx.x;
    int row = g >> 7, c = g & 127;
    float v = h[g] * W3[g];
    unsafeAtomicAdd(&acc[(size_t)nl[row] * 128 + c], v);
}

extern "C" void kernel_launch(void* const* d_in, const int* in_sizes, int n_in,
                              void* d_out, int out_size, void* d_ws, size_t ws_size,
                              hipStream_t stream) {
    const float* features = (const float*)d_in[0];
    const float* dist = (const float*)d_in[1];
    const float* ang = (const float*)d_in[2];
    const float* rij = (const float*)d_in[3];
    const float* rik = (const float*)d_in[4];
    const int* nl = (const int*)d_in[5];
    const int* tri = (const int*)d_in[6];
    const float* W_pre = (const float*)d_in[7];
    const float* tbW1 = (const float*)d_in[8];
    const float* tbW2 = (const float*)d_in[9];
    const float* tbG1 = (const float*)d_in[10];
    const float* tbG2 = (const float*)d_in[11];
    const float* thW1 = (const float*)d_in[12];
    const float* thW2 = (const float*)d_in[13];
    const float* thG1 = (const float*)d_in[14];
    const float* thG2 = (const float*)d_in[15];
    const float* W_post = (const float*)d_in[16];
    float* out = (float*)d_out;

    float* h   = (float*)d_ws;                     // 2,560,000
    float* acc = h + (size_t)NAT * CH;             // 2,560,000
    float* W3  = acc + (size_t)NAT * CH;           // 2,560,000
    float* lut = W3 + (size_t)NAT * CH;            // (NB+1)*128 = 524,416
    int* tcnt  = (int*)(lut + (size_t)(NB + 1) * CH);
    int* toff  = tcnt + NAT;                       // NAT+1
    int* tcur  = toff + NAT + 1;
    int* ecnt  = tcur + NAT;
    int* eoff  = ecnt + NAT;                       // NAT+1
    int* ecur  = eoff + NAT + 1;
    int* tsorted = ecur + NAT;                     // NT
    int* esorted = tsorted + NT;                   // NE
    // total ~44 MB

    hipMemsetAsync(tcnt, 0, (size_t)NAT * sizeof(int), stream);
    hipMemsetAsync(ecnt, 0, (size_t)NAT * sizeof(int), stream);

    gemm128<<<NAT / 32, 256, 0, stream>>>(features, W_pre, h);
    build_lut<<<NB + 1, 128, 0, stream>>>(tbW1, tbW2, tbG1, tbG2, lut);
    hist_k<<<1024, 256, 0, stream>>>(tri, nl, tcnt, ecnt);
    scan20k<<<2, 1024, 0, stream>>>(tcnt, toff, tcur, ecnt, eoff, ecur);
    scatter_k<<<1024, 256, 0, stream>>>(tri, nl, tcur, ecur, tsorted, esorted);
    twobody_sorted<<<1280, 256, 0, stream>>>(dist, nl, h, lut, eoff, esorted, acc);
    threebody_sorted<<<1280, 256, 0, stream>>>(rij, rik, ang, tsorted, toff,
                                               thW1, thW2, thG1, thG2, W3);
    inject<<<NAT * CH / 256, 256, 0, stream>>>(h, W3, nl, acc);
    gemm128<<<NAT / 32, 256, 0, stream>>>(acc, W_post, out);
}